// Round 11
// baseline (304.820 us; speedup 1.0000x reference)
//
#include <hip/hip_runtime.h>
#include <math.h>

#define Bn   128
#define Cn   2048
#define Hn   24
#define Wn   12
#define HID  768
#define NIN  1536
#define NST  16
#define DTR  48
#define Ln   9
#define Mn   (Bn*Ln)   // 1152
#define XKS  16        // xproj split-K slices

typedef __bf16 bf16x8 __attribute__((ext_vector_type(8)));
typedef float  f32x4  __attribute__((ext_vector_type(4)));

// async global->LDS, 16B per lane; LDS dest is wave-uniform base + lane*16
#define GLOAD16(gsrc, ldst) \
  __builtin_amdgcn_global_load_lds((const __attribute__((address_space(1))) void*)(gsrc), \
                                   (__attribute__((address_space(3))) void*)(ldst), 16, 0, 0)

__device__ __forceinline__ unsigned short f2bf(float f) {
  unsigned u = __float_as_uint(f);
  u += 0x7fffu + ((u >> 16) & 1u);           // round-to-nearest-even
  return (unsigned short)(u >> 16);
}
__device__ __forceinline__ float bf2f(unsigned short h) {
  return __uint_as_float(((unsigned)h) << 16);
}
__device__ __forceinline__ void split_bf(float f, unsigned short& hi, unsigned short& lo) {
  hi = f2bf(f);
  lo = f2bf(f - bf2f(hi));
}
// interleaved hi/lo column index: per 32-k block, [hi 0..31 | lo 0..31]
__device__ __forceinline__ int col2(int k) { return ((k >> 5) << 6) + (k & 31); }

// ---------------- prep: 3 weight transposes + pooling, one launch ----------------
__global__ __launch_bounds__(256) void prep_kernel(const float* __restrict__ pe_w,
    const float* __restrict__ in_w, const float* __restrict__ out_w,
    const float* __restrict__ x,
    unsigned short* __restrict__ peT2, unsigned short* __restrict__ inT2,
    unsigned short* __restrict__ outT2, unsigned short* __restrict__ tok2) {
  __shared__ char smem[32 * 73 * 16];                 // union: pool raw / tconv tile
  int bid = blockIdx.x;
  int t = threadIdx.x;
  if (bid < 6912) {
    float (*tile)[33] = reinterpret_cast<float (*)[33]>(smem);
    const float* W; unsigned short* T2; int K, N, nb, kb;
    if (bid < 1536)      { W = pe_w;  T2 = peT2;  K = Cn;  N = HID;     nb = bid % 24; kb = bid / 24; }
    else if (bid < 3840) { int q = bid - 1536; W = in_w;  T2 = inT2;  K = HID; N = 2 * NIN; nb = q % 96; kb = q / 96; }
    else                 { int q = bid - 3840; W = out_w; T2 = outT2; K = NIN; N = Cn;      nb = q % 64; kb = q / 64; }
    int kl = t >> 3, n4 = (t & 7) * 4;
    float4 v = *reinterpret_cast<const float4*>(W + (size_t)(kb * 32 + kl) * N + nb * 32 + n4);
    tile[kl][n4] = v.x; tile[kl][n4 + 1] = v.y; tile[kl][n4 + 2] = v.z; tile[kl][n4 + 3] = v.w;
    __syncthreads();
    int nl = t >> 3, k4 = (t & 7) * 4;
    unsigned short hi[4], lo[4];
    #pragma unroll
    for (int i = 0; i < 4; ++i) split_bf(tile[k4 + i][nl], hi[i], lo[i]);
    size_t base = (size_t)(nb * 32 + nl) * (2 * K) + kb * 64 + k4;
    uint2 ph, pl;
    ph.x = (unsigned)hi[0] | ((unsigned)hi[1] << 16);
    ph.y = (unsigned)hi[2] | ((unsigned)hi[3] << 16);
    pl.x = (unsigned)lo[0] | ((unsigned)lo[1] << 16);
    pl.y = (unsigned)lo[2] | ((unsigned)lo[3] << 16);
    *reinterpret_cast<uint2*>(T2 + base)      = ph;
    *reinterpret_cast<uint2*>(T2 + base + 32) = pl;
  } else {
    float4 (*raw)[73] = reinterpret_cast<float4 (*)[73]>(smem);
    int blk = bid - 6912;                             // Bn * (Cn/32) = 8192
    int b = blk >> 6, cg = blk & 63;
    const float4* src = reinterpret_cast<const float4*>(x) + (size_t)(b * Cn + cg * 32) * 72;
    #pragma unroll
    for (int it = 0; it < 9; ++it) {
      int li = it * 256 + t;
      raw[li / 72][li % 72] = src[li];
    }
    __syncthreads();
    for (int cell = t; cell < 288; cell += 256) {
      int c = cell / 9, p = cell % 9, i = p / 3, j = p % 3;
      float s = 0.f;
      #pragma unroll
      for (int k = 0; k < 8; ++k) {
        float4 v = raw[c][(i * 8 + k) * 3 + j];
        s += (v.x + v.y) + (v.z + v.w);
      }
      s *= (1.0f / 32.0f);
      unsigned short hi, lo;
      split_bf(s, hi, lo);
      int cglob = cg * 32 + c;
      size_t base = ((size_t)(b * Ln + p)) * (2 * Cn) + col2(cglob);
      tok2[base] = hi; tok2[base + 32] = lo;
    }
  }
}

// ------------- split-bf16 MFMA GEMM, 128x128 BK=32, SINGLE-buffer (m97 2-barrier) -------
// 32 KB LDS -> 3 blocks/CU (vs 2 with dbuf). XCD-aware bijective block swizzle kept.
__global__ __launch_bounds__(256) void mgemm_kernel(
    const unsigned short* __restrict__ A2, const unsigned short* __restrict__ B2,
    float* __restrict__ Cout, int M, int N, int K, int Ksub) {
  // --- XCD swizzle: hw block id -> work tile id (chunked per XCD) ---
  int nwg = gridDim.x * gridDim.y * gridDim.z;
  int hw  = blockIdx.x + gridDim.x * (blockIdx.y + gridDim.y * blockIdx.z);
  int cpx = nwg >> 3;
  int wid = (hw & 7) * cpx + (hw >> 3);
  int bx = wid % gridDim.x;
  int rem = wid / gridDim.x;
  int by = rem % gridDim.y;
  int bz = rem / gridDim.y;

  __shared__ unsigned short As[128][64];
  __shared__ unsigned short Bs[128][64];
  int t = threadIdx.x;
  int bm = by * 128, bn = bx * 128;
  int wave = t >> 6, lane = t & 63;
  int wr = (wave >> 1) * 64, wc = (wave & 1) * 64;
  int lr = lane & 15, lk = lane >> 4;

  int l3 = lane >> 3, c8 = lane & 7;
  int sc = c8 ^ l3;
  size_t koff = (size_t)bz * 2 * (size_t)Ksub;
  const unsigned short* Ab = A2 + (size_t)(bm + wave * 32 + l3) * (2 * (size_t)K) + koff + sc * 8;
  const unsigned short* Bb = B2 + (size_t)(bn + wave * 32 + l3) * (2 * (size_t)K) + koff + sc * 8;
  size_t rstep = (size_t)8 * 2 * K;
  unsigned short* AsW = &As[wave * 32][0];
  unsigned short* BsW = &Bs[wave * 32][0];

  f32x4 acc[4][4];
  #pragma unroll
  for (int m = 0; m < 4; ++m)
    #pragma unroll
    for (int n = 0; n < 4; ++n) acc[m][n] = {0.f, 0.f, 0.f, 0.f};

  for (int kk = 0; kk < Ksub; kk += 32) {
    __syncthreads();                                  // all waves done reading LDS
    #pragma unroll
    for (int q = 0; q < 4; ++q) {
      GLOAD16(Ab + q * rstep + kk * 2, AsW + q * 8 * 64);
      GLOAD16(Bb + q * rstep + kk * 2, BsW + q * 8 * 64);
    }
    __syncthreads();                                  // vmcnt drain -> LDS ready

    bf16x8 ah[4], al[4], bh[4], bl[4];
    #pragma unroll
    for (int m = 0; m < 4; ++m) {
      int ar = wr + m * 16 + lr;
      ah[m] = *reinterpret_cast<const bf16x8*>(&As[ar][((lk    ) ^ (ar & 7)) * 8]);
      al[m] = *reinterpret_cast<const bf16x8*>(&As[ar][((4 + lk) ^ (ar & 7)) * 8]);
    }
    #pragma unroll
    for (int n = 0; n < 4; ++n) {
      int br = wc + n * 16 + lr;
      bh[n] = *reinterpret_cast<const bf16x8*>(&Bs[br][((lk    ) ^ (br & 7)) * 8]);
      bl[n] = *reinterpret_cast<const bf16x8*>(&Bs[br][((4 + lk) ^ (br & 7)) * 8]);
    }
    #pragma unroll
    for (int m = 0; m < 4; ++m)
      #pragma unroll
      for (int n = 0; n < 4; ++n) {
        acc[m][n] = __builtin_amdgcn_mfma_f32_16x16x32_bf16(ah[m], bh[n], acc[m][n], 0, 0, 0);
        acc[m][n] = __builtin_amdgcn_mfma_f32_16x16x32_bf16(ah[m], bl[n], acc[m][n], 0, 0, 0);
        acc[m][n] = __builtin_amdgcn_mfma_f32_16x16x32_bf16(al[m], bh[n], acc[m][n], 0, 0, 0);
      }
  }

  float* dst = Cout + (size_t)bz * M * N;
  #pragma unroll
  for (int m = 0; m < 4; ++m)
    #pragma unroll
    for (int n = 0; n < 4; ++n) {
      int col = bn + wc + n * 16 + lr;
      #pragma unroll
      for (int r = 0; r < 4; ++r) {
        int row = bm + wr + m * 16 + lk * 4 + r;
        dst[(size_t)row * N + col] = acc[m][n][r];
      }
    }
}

// conv+silu recompute for 4 consecutive channels d0..d0+3 at token row R (2 part2 slices)
__device__ __forceinline__ float4 conv_silu4(const float* __restrict__ p0,
    const float* __restrict__ p1, const float* __restrict__ cw,
    const float* __restrict__ cb, int R, int d0) {
  int bq = R / 9, pq = R - bq * 9;
  size_t rb = (size_t)R * (2 * NIN) + d0;
  float4 a0 = *reinterpret_cast<const float4*>(p0 + rb);
  float4 a1 = *reinterpret_cast<const float4*>(p1 + rb);
  float cx[4] = {a0.x + a1.x, a0.y + a1.y, a0.z + a1.z, a0.w + a1.w};
  float cm[4] = {0.f, 0.f, 0.f, 0.f}, cp[4] = {0.f, 0.f, 0.f, 0.f};
  if (pq > 0) {
    float4 m0 = *reinterpret_cast<const float4*>(p0 + rb - 2 * NIN);
    float4 m1 = *reinterpret_cast<const float4*>(p1 + rb - 2 * NIN);
    cm[0] = m0.x + m1.x; cm[1] = m0.y + m1.y; cm[2] = m0.z + m1.z; cm[3] = m0.w + m1.w;
  }
  if (pq < Ln - 1) {
    float4 q0 = *reinterpret_cast<const float4*>(p0 + rb + 2 * NIN);
    float4 q1 = *reinterpret_cast<const float4*>(p1 + rb + 2 * NIN);
    cp[0] = q0.x + q1.x; cp[1] = q0.y + q1.y; cp[2] = q0.z + q1.z; cp[3] = q0.w + q1.w;
  }
  float4 w0 = *reinterpret_cast<const float4*>(cw + 3 * d0);
  float4 w1 = *reinterpret_cast<const float4*>(cw + 3 * d0 + 4);
  float4 w2 = *reinterpret_cast<const float4*>(cw + 3 * d0 + 8);
  float wf[12] = {w0.x, w0.y, w0.z, w0.w, w1.x, w1.y, w1.z, w1.w, w2.x, w2.y, w2.z, w2.w};
  float4 cb4 = *reinterpret_cast<const float4*>(cb + d0);
  float cbf[4] = {cb4.x, cb4.y, cb4.z, cb4.w};
  float r[4];
  #pragma unroll
  for (int i = 0; i < 4; ++i) {
    float a = cbf[i] + cm[i] * wf[3 * i] + cx[i] * wf[3 * i + 1] + cp[i] * wf[3 * i + 2];
    r[i] = a / (1.0f + __expf(-a));
  }
  return make_float4(r[0], r[1], r[2], r[3]);
}

// ---------------- xproj split-K partials (fp32), conv+silu fused into A staging ----------
__global__ __launch_bounds__(256) void xproj_kernel(const float* __restrict__ part2,
    const float* __restrict__ cw, const float* __restrict__ cb,
    const float* __restrict__ w, float* __restrict__ part) {
  __shared__ float at[64][44];
  __shared__ float wt[32][80];
  int kc = blockIdx.x, mt = blockIdx.y;
  int t = threadIdx.x;
  int tx = t & 15, ty = t >> 4;
  float acc[4][5] = {};
  int sr = t >> 3, sc4 = (t & 7) * 4;
  const float* p0 = part2;
  const float* p1 = part2 + (size_t)Mn * 2 * NIN;
  for (int k0 = kc * 96; k0 < kc * 96 + 96; k0 += 32) {
    float4 v0 = conv_silu4(p0, p1, cw, cb, mt * 64 + sr,      k0 + sc4);
    float4 v1 = conv_silu4(p0, p1, cw, cb, mt * 64 + sr + 32, k0 + sc4);
    __syncthreads();
    *reinterpret_cast<float4*>(&at[sr][sc4])      = v0;
    *reinterpret_cast<float4*>(&at[sr + 32][sc4]) = v1;
    for (int i = t; i < 32 * 80; i += 256)
      wt[i / 80][i % 80] = w[(size_t)(k0 + i / 80) * 80 + i % 80];
    __syncthreads();
    #pragma unroll
    for (int kk = 0; kk < 32; ++kk) {
      float a0[4], b0[5];
      #pragma unroll
      for (int i = 0; i < 4; ++i) a0[i] = at[ty * 4 + i][kk];
      #pragma unroll
      for (int j = 0; j < 5; ++j) b0[j] = wt[kk][tx + 16 * j];
      #pragma unroll
      for (int i = 0; i < 4; ++i)
        #pragma unroll
        for (int j = 0; j < 5; ++j)
          acc[i][j] = fmaf(a0[i], b0[j], acc[i][j]);
    }
  }
  #pragma unroll
  for (int i = 0; i < 4; ++i)
    #pragma unroll
    for (int j = 0; j < 5; ++j)
      part[((size_t)kc * Mn + mt * 64 + ty * 4 + i) * 80 + tx + 16 * j] = acc[i][j];
}

// ---------------- fused: split-K reduce + pe_b bias + LayerNorm -> interleaved h2 --------
__global__ __launch_bounds__(256) void ln_kernel(const float* __restrict__ part1,
    const float* __restrict__ peb, const float* __restrict__ g, const float* __restrict__ be,
    unsigned short* __restrict__ h2) {
  int row = blockIdx.x;
  int t = threadIdx.x;
  float vq[3];
  #pragma unroll
  for (int q = 0; q < 3; ++q) {
    int c = t + q * 256;
    float v = peb[c];
    #pragma unroll
    for (int ks = 0; ks < 8; ++ks)
      v += part1[((size_t)ks * Mn + row) * HID + c];
    vq[q] = v;
  }
  float s  = vq[0] + vq[1] + vq[2];
  float s2 = vq[0] * vq[0] + vq[1] * vq[1] + vq[2] * vq[2];
  #pragma unroll
  for (int o = 32; o > 0; o >>= 1) {
    s  += __shfl_down(s,  o, 64);
    s2 += __shfl_down(s2, o, 64);
  }
  __shared__ float red[8];
  int wid = t >> 6, lane = t & 63;
  if (lane == 0) { red[wid] = s; red[4 + wid] = s2; }
  __syncthreads();
  float S  = red[0] + red[1] + red[2] + red[3];
  float S2 = red[4] + red[5] + red[6] + red[7];
  float mu  = S * (1.0f / HID);
  float var = S2 * (1.0f / HID) - mu * mu;
  float inv = rsqrtf(var + 1e-5f);
  #pragma unroll
  for (int q = 0; q < 3; ++q) {
    int c = t + q * 256;
    float hv = (vq[q] - mu) * inv * g[c] + be[c];
    unsigned short hi, lo;
    split_bf(hv, hi, lo);
    size_t base = (size_t)row * (2 * HID) + col2(c);
    h2[base] = hi; h2[base + 32] = lo;
  }
}

// -- fused scan: xproj reduce + dt-proj + softplus + conv-recompute + scan + D + z-gate --
__global__ __launch_bounds__(256) void scan_kernel(const float* __restrict__ partx,
    const float* __restrict__ A_log, const float* __restrict__ Dp,
    const float* __restrict__ part2, const float* __restrict__ dtw,
    const float* __restrict__ dtb, const float* __restrict__ cw,
    const float* __restrict__ cb, unsigned short* __restrict__ ya2) {
  __shared__ float wdt[DTR * 256];                    // 48 KB
  __shared__ float dbc9[Ln][DTR];
  __shared__ float Bsh[Ln][NST], Csh[Ln][NST];
  int b      = blockIdx.x / (NIN / 256);
  int dchunk = blockIdx.x % (NIN / 256);
  int t = threadIdx.x;
  float4* w4 = reinterpret_cast<float4*>(wdt);
  #pragma unroll
  for (int it = 0; it < 12; ++it) {
    int i4 = it * 256 + t;
    int k = i4 >> 6, c4 = i4 & 63;
    w4[i4] = *reinterpret_cast<const float4*>(dtw + (size_t)k * NIN + dchunk * 256 + c4 * 4);
  }
  for (int i = t; i < Ln * 80; i += 256) {
    int p = i / 80, k = i - p * 80;
    size_t off = (size_t)(b * Ln + p) * 80 + k;
    float s = 0.f;
    #pragma unroll
    for (int ks = 0; ks < XKS; ++ks) s += partx[(size_t)ks * (Mn * 80) + off];
    if (k < DTR)            dbc9[p][k] = s;
    else if (k < DTR + NST) Bsh[p][k - DTR] = s;
    else                    Csh[p][k - DTR - NST] = s;
  }
  __syncthreads();
  int d = dchunk * 256 + t;
  float Ar[NST];
  #pragma unroll
  for (int n = 0; n < NST; ++n) Ar[n] = -__expf(A_log[(size_t)d * NST + n]);
  float s[NST];
  #pragma unroll
  for (int n = 0; n < NST; ++n) s[n] = 0.0f;
  float Dv = Dp[d];
  float bt = dtb[d];
  float w0 = cw[3 * d], w1 = cw[3 * d + 1], w2 = cw[3 * d + 2];
  float cbv = cb[d];
  int cc = col2(d);
  const float* px0 = part2 + d;                       // x-half
  const float* px1 = px0 + (size_t)Mn * 2 * NIN;
  const float* z0  = part2 + NIN + d;                 // z-half
  const float* z1  = z0 + (size_t)Mn * 2 * NIN;
  size_t row0 = (size_t)(b * Ln) * (2 * NIN);
  float xm = 0.f;
  float x0 = px0[row0] + px1[row0];
  for (int p = 0; p < Ln; ++p) {
    size_t roff = row0 + (size_t)p * (2 * NIN);
    float xp = 0.f;
    if (p < Ln - 1) xp = px0[roff + 2 * NIN] + px1[roff + 2 * NIN];
    float a0 = cbv + xm * w0 + x0 * w1 + xp * w2;
    float u = a0 / (1.0f + __expf(-a0));              // silu(conv)
    float a = bt;
    #pragma unroll
    for (int k = 0; k < DTR; ++k) a = fmaf(dbc9[p][k], wdt[k * 256 + t], a);
    float dl = fmaxf(a, 0.0f) + log1pf(__expf(-fabsf(a)));
    float du = dl * u;
    float y = 0.0f;
    #pragma unroll
    for (int n = 0; n < NST; ++n) {
      float dA = __expf(dl * Ar[n]);
      s[n] = dA * s[n] + du * Bsh[p][n];
      y += s[n] * Csh[p][n];
    }
    float zv = z0[roff] + z1[roff];
    float sz = zv / (1.0f + __expf(-zv));
    float yv = (y + u * Dv) * sz;
    unsigned short hi, lo;
    split_bf(yv, hi, lo);
    ya2[roff + cc] = hi; ya2[roff + cc + 32] = lo;
    xm = x0; x0 = xp;
  }
}

// -------- fused: split-K reduce + transpose + bilinear resize, coalesced writes --------
__global__ __launch_bounds__(256) void resize_kernel(const float* __restrict__ part3,
                                                     float* __restrict__ out) {
  __shared__ float v[32][10];
  int blk = blockIdx.x;                               // Bn * (Cn/32) = 8192
  int b = blk >> 6, cg = blk & 63;
  int t = threadIdx.x;
  size_t MN3 = (size_t)Mn * Cn;
  for (int i = t; i < 288; i += 256) {
    int p = i >> 5, c = i & 31;
    size_t base = (size_t)(b * Ln + p) * Cn + cg * 32 + c;
    v[c][p] = part3[base] + part3[base + MN3];
  }
  __syncthreads();
  int ch = t >> 3, sub = t & 7;
  float* dst = out + ((size_t)b * Cn + cg * 32 + ch) * 288;
  #pragma unroll
  for (int q = 0; q < 9; ++q) {
    int f = sub + q * 8;
    int y = f / 3, xq = f - y * 3;
    float fy  = (y + 0.5f) * 0.125f - 0.5f;
    float fyf = floorf(fy);
    float wy  = fy - fyf;
    int yy = (int)fyf;
    int y0 = min(2, max(0, yy)), y1 = min(2, max(0, yy + 1));
    float rr[3];
    #pragma unroll
    for (int j = 0; j < 3; ++j)
      rr[j] = v[ch][y0 * 3 + j] * (1.0f - wy) + v[ch][y1 * 3 + j] * wy;
    float ov[4];
    #pragma unroll
    for (int xi = 0; xi < 4; ++xi) {
      int xo = xq * 4 + xi;
      float fx  = (xo + 0.5f) * 0.25f - 0.5f;
      float fxf = floorf(fx);
      float wx  = fx - fxf;
      int xx = (int)fxf;
      int x0 = min(2, max(0, xx)), x1 = min(2, max(0, xx + 1));
      ov[xi] = rr[x0] * (1.0f - wx) + rr[x1] * wx;
    }
    *reinterpret_cast<float4*>(dst + f * 4) = make_float4(ov[0], ov[1], ov[2], ov[3]);
  }
}

extern "C" void kernel_launch(void* const* d_in, const int* in_sizes, int n_in,
                              void* d_out, int out_size, void* d_ws, size_t ws_size,
                              hipStream_t stream) {
  const float* x        = (const float*)d_in[0];
  const float* pe_w     = (const float*)d_in[1];
  const float* pe_b     = (const float*)d_in[2];
  const float* ln_g     = (const float*)d_in[3];
  const float* ln_b     = (const float*)d_in[4];
  const float* in_w     = (const float*)d_in[5];
  const float* conv_w   = (const float*)d_in[6];
  const float* conv_b   = (const float*)d_in[7];
  const float* A_log    = (const float*)d_in[8];
  const float* xproj_w  = (const float*)d_in[9];
  const float* dtproj_w = (const float*)d_in[10];
  const float* dtproj_b = (const float*)d_in[11];
  const float* D_param  = (const float*)d_in[12];
  const float* out_w    = (const float*)d_in[13];
  float* out = (float*)d_out;
  char* ws = (char*)d_ws;

  size_t o = 0;
  auto alloc = [&](size_t bytes) { size_t r = o; o += (bytes + 255) & ~(size_t)255; return r; };
  unsigned short* tok2  = (unsigned short*)(ws + alloc((size_t)Mn * 2 * Cn * 2));
  unsigned short* peT2  = (unsigned short*)(ws + alloc((size_t)HID * 2 * Cn * 2));
  unsigned short* inT2  = (unsigned short*)(ws + alloc((size_t)2 * NIN * 2 * HID * 2));
  unsigned short* outT2 = (unsigned short*)(ws + alloc((size_t)Cn * 2 * NIN * 2));
  unsigned short* h2    = (unsigned short*)(ws + alloc((size_t)Mn * 2 * HID * 2));
  unsigned short* ya2   = (unsigned short*)(ws + alloc((size_t)Mn * 2 * NIN * 2));
  float* part1 = (float*)(ws + alloc((size_t)8 * Mn * HID * 4));
  float* part2 = (float*)(ws + alloc((size_t)2 * Mn * 2 * NIN * 4));
  float* part3 = (float*)(ws + alloc((size_t)2 * Mn * Cn * 4));
  float* partx = (float*)(ws + alloc((size_t)XKS * Mn * 80 * 4));

  // prep: weight transposes (6912 blocks) + pooling (8192 blocks)
  prep_kernel<<<15104, 256, 0, stream>>>(pe_w, in_w, out_w, x, peT2, inT2, outT2, tok2);

  // tok @ pe_w : M=1152 N=768 K=2048, split-K=8 -> grid 432 (6*9*8)
  mgemm_kernel<<<dim3(HID / 128, Mn / 128, 8), 256, 0, stream>>>(
      tok2, peT2, part1, Mn, HID, Cn, Cn / 8);
  ln_kernel<<<Mn, 256, 0, stream>>>(part1, pe_b, ln_g, ln_b, h2);
  // h @ in_w : M=1152 N=3072 K=768, split-K=2 -> grid 432 (24*9*2)
  mgemm_kernel<<<dim3(2 * NIN / 128, Mn / 128, 2), 256, 0, stream>>>(
      h2, inT2, part2, Mn, 2 * NIN, HID, HID / 2);
  xproj_kernel<<<dim3(XKS, Mn / 64), 256, 0, stream>>>(part2, conv_w, conv_b, xproj_w, partx);
  scan_kernel<<<Bn * (NIN / 256), 256, 0, stream>>>(
      partx, A_log, D_param, part2, dtproj_w, dtproj_b, conv_w, conv_b, ya2);
  // ya @ out_w : M=1152 N=2048 K=1536, split-K=2 -> grid 288 (16*9*2)
  mgemm_kernel<<<dim3(Cn / 128, Mn / 128, 2), 256, 0, stream>>>(
      ya2, outT2, part3, Mn, Cn, NIN, NIN / 2);
  resize_kernel<<<Bn * (Cn / 32), 256, 0, stream>>>(part3, out);
}

// Round 12
// 297.634 us; speedup vs baseline: 1.0241x; 1.0241x over previous
//
#include <hip/hip_runtime.h>
#include <math.h>

#define Bn   128
#define Cn   2048
#define Hn   24
#define Wn   12
#define HID  768
#define NIN  1536
#define NST  16
#define DTR  48
#define Ln   9
#define Mn   (Bn*Ln)   // 1152
#define XKS  16        // xproj split-K slices
#define KS2  3         // GEMM2 split-K slices
#define KS3  4         // GEMM3 split-K slices

typedef __bf16 bf16x8 __attribute__((ext_vector_type(8)));
typedef float  f32x4  __attribute__((ext_vector_type(4)));

// async global->LDS, 16B per lane; LDS dest is wave-uniform base + lane*16
#define GLOAD16(gsrc, ldst) \
  __builtin_amdgcn_global_load_lds((const __attribute__((address_space(1))) void*)(gsrc), \
                                   (__attribute__((address_space(3))) void*)(ldst), 16, 0, 0)

__device__ __forceinline__ unsigned short f2bf(float f) {
  unsigned u = __float_as_uint(f);
  u += 0x7fffu + ((u >> 16) & 1u);           // round-to-nearest-even
  return (unsigned short)(u >> 16);
}
__device__ __forceinline__ float bf2f(unsigned short h) {
  return __uint_as_float(((unsigned)h) << 16);
}
__device__ __forceinline__ void split_bf(float f, unsigned short& hi, unsigned short& lo) {
  hi = f2bf(f);
  lo = f2bf(f - bf2f(hi));
}
// interleaved hi/lo column index: per 32-k block, [hi 0..31 | lo 0..31]
__device__ __forceinline__ int col2(int k) { return ((k >> 5) << 6) + (k & 31); }

// ---------------- prep: 3 weight transposes + pooling, one launch ----------------
__global__ __launch_bounds__(256) void prep_kernel(const float* __restrict__ pe_w,
    const float* __restrict__ in_w, const float* __restrict__ out_w,
    const float* __restrict__ x,
    unsigned short* __restrict__ peT2, unsigned short* __restrict__ inT2,
    unsigned short* __restrict__ outT2, unsigned short* __restrict__ tok2) {
  __shared__ char smem[32 * 73 * 16];                 // union: pool raw / tconv tile
  int bid = blockIdx.x;
  int t = threadIdx.x;
  if (bid < 6912) {
    float (*tile)[33] = reinterpret_cast<float (*)[33]>(smem);
    const float* W; unsigned short* T2; int K, N, nb, kb;
    if (bid < 1536)      { W = pe_w;  T2 = peT2;  K = Cn;  N = HID;     nb = bid % 24; kb = bid / 24; }
    else if (bid < 3840) { int q = bid - 1536; W = in_w;  T2 = inT2;  K = HID; N = 2 * NIN; nb = q % 96; kb = q / 96; }
    else                 { int q = bid - 3840; W = out_w; T2 = outT2; K = NIN; N = Cn;      nb = q % 64; kb = q / 64; }
    int kl = t >> 3, n4 = (t & 7) * 4;
    float4 v = *reinterpret_cast<const float4*>(W + (size_t)(kb * 32 + kl) * N + nb * 32 + n4);
    tile[kl][n4] = v.x; tile[kl][n4 + 1] = v.y; tile[kl][n4 + 2] = v.z; tile[kl][n4 + 3] = v.w;
    __syncthreads();
    int nl = t >> 3, k4 = (t & 7) * 4;
    unsigned short hi[4], lo[4];
    #pragma unroll
    for (int i = 0; i < 4; ++i) split_bf(tile[k4 + i][nl], hi[i], lo[i]);
    size_t base = (size_t)(nb * 32 + nl) * (2 * K) + kb * 64 + k4;
    uint2 ph, pl;
    ph.x = (unsigned)hi[0] | ((unsigned)hi[1] << 16);
    ph.y = (unsigned)hi[2] | ((unsigned)hi[3] << 16);
    pl.x = (unsigned)lo[0] | ((unsigned)lo[1] << 16);
    pl.y = (unsigned)lo[2] | ((unsigned)lo[3] << 16);
    *reinterpret_cast<uint2*>(T2 + base)      = ph;
    *reinterpret_cast<uint2*>(T2 + base + 32) = pl;
  } else {
    float4 (*raw)[73] = reinterpret_cast<float4 (*)[73]>(smem);
    int blk = bid - 6912;                             // Bn * (Cn/32) = 8192
    int b = blk >> 6, cg = blk & 63;
    const float4* src = reinterpret_cast<const float4*>(x) + (size_t)(b * Cn + cg * 32) * 72;
    #pragma unroll
    for (int it = 0; it < 9; ++it) {
      int li = it * 256 + t;
      raw[li / 72][li % 72] = src[li];
    }
    __syncthreads();
    for (int cell = t; cell < 288; cell += 256) {
      int c = cell / 9, p = cell % 9, i = p / 3, j = p % 3;
      float s = 0.f;
      #pragma unroll
      for (int k = 0; k < 8; ++k) {
        float4 v = raw[c][(i * 8 + k) * 3 + j];
        s += (v.x + v.y) + (v.z + v.w);
      }
      s *= (1.0f / 32.0f);
      unsigned short hi, lo;
      split_bf(s, hi, lo);
      int cglob = cg * 32 + c;
      size_t base = ((size_t)(b * Ln + p)) * (2 * Cn) + col2(cglob);
      tok2[base] = hi; tok2[base + 32] = lo;
    }
  }
}

// ------------- split-bf16 MFMA GEMM, 128x128 BK=32, single-buffer (m97 2-barrier) -------
// 32 KB LDS -> 3 blocks/CU residency; XCD-aware bijective block swizzle.
__global__ __launch_bounds__(256) void mgemm_kernel(
    const unsigned short* __restrict__ A2, const unsigned short* __restrict__ B2,
    float* __restrict__ Cout, int M, int N, int K, int Ksub) {
  // --- XCD swizzle: hw block id -> work tile id (chunked per XCD) ---
  int nwg = gridDim.x * gridDim.y * gridDim.z;
  int hw  = blockIdx.x + gridDim.x * (blockIdx.y + gridDim.y * blockIdx.z);
  int cpx = nwg >> 3;
  int wid = (hw & 7) * cpx + (hw >> 3);
  int bx = wid % gridDim.x;
  int rem = wid / gridDim.x;
  int by = rem % gridDim.y;
  int bz = rem / gridDim.y;

  __shared__ unsigned short As[128][64];
  __shared__ unsigned short Bs[128][64];
  int t = threadIdx.x;
  int bm = by * 128, bn = bx * 128;
  int wave = t >> 6, lane = t & 63;
  int wr = (wave >> 1) * 64, wc = (wave & 1) * 64;
  int lr = lane & 15, lk = lane >> 4;

  int l3 = lane >> 3, c8 = lane & 7;
  int sc = c8 ^ l3;
  size_t koff = (size_t)bz * 2 * (size_t)Ksub;
  const unsigned short* Ab = A2 + (size_t)(bm + wave * 32 + l3) * (2 * (size_t)K) + koff + sc * 8;
  const unsigned short* Bb = B2 + (size_t)(bn + wave * 32 + l3) * (2 * (size_t)K) + koff + sc * 8;
  size_t rstep = (size_t)8 * 2 * K;
  unsigned short* AsW = &As[wave * 32][0];
  unsigned short* BsW = &Bs[wave * 32][0];

  f32x4 acc[4][4];
  #pragma unroll
  for (int m = 0; m < 4; ++m)
    #pragma unroll
    for (int n = 0; n < 4; ++n) acc[m][n] = {0.f, 0.f, 0.f, 0.f};

  for (int kk = 0; kk < Ksub; kk += 32) {
    __syncthreads();                                  // all waves done reading LDS
    #pragma unroll
    for (int q = 0; q < 4; ++q) {
      GLOAD16(Ab + q * rstep + kk * 2, AsW + q * 8 * 64);
      GLOAD16(Bb + q * rstep + kk * 2, BsW + q * 8 * 64);
    }
    __syncthreads();                                  // vmcnt drain -> LDS ready

    bf16x8 ah[4], al[4], bh[4], bl[4];
    #pragma unroll
    for (int m = 0; m < 4; ++m) {
      int ar = wr + m * 16 + lr;
      ah[m] = *reinterpret_cast<const bf16x8*>(&As[ar][((lk    ) ^ (ar & 7)) * 8]);
      al[m] = *reinterpret_cast<const bf16x8*>(&As[ar][((4 + lk) ^ (ar & 7)) * 8]);
    }
    #pragma unroll
    for (int n = 0; n < 4; ++n) {
      int br = wc + n * 16 + lr;
      bh[n] = *reinterpret_cast<const bf16x8*>(&Bs[br][((lk    ) ^ (br & 7)) * 8]);
      bl[n] = *reinterpret_cast<const bf16x8*>(&Bs[br][((4 + lk) ^ (br & 7)) * 8]);
    }
    #pragma unroll
    for (int m = 0; m < 4; ++m)
      #pragma unroll
      for (int n = 0; n < 4; ++n) {
        acc[m][n] = __builtin_amdgcn_mfma_f32_16x16x32_bf16(ah[m], bh[n], acc[m][n], 0, 0, 0);
        acc[m][n] = __builtin_amdgcn_mfma_f32_16x16x32_bf16(ah[m], bl[n], acc[m][n], 0, 0, 0);
        acc[m][n] = __builtin_amdgcn_mfma_f32_16x16x32_bf16(al[m], bh[n], acc[m][n], 0, 0, 0);
      }
  }

  float* dst = Cout + (size_t)bz * M * N;
  #pragma unroll
  for (int m = 0; m < 4; ++m)
    #pragma unroll
    for (int n = 0; n < 4; ++n) {
      int col = bn + wc + n * 16 + lr;
      #pragma unroll
      for (int r = 0; r < 4; ++r) {
        int row = bm + wr + m * 16 + lk * 4 + r;
        dst[(size_t)row * N + col] = acc[m][n][r];
      }
    }
}

// conv+silu recompute for 4 channels d0..d0+3 at token row R (sums KS2 part2 slices)
__device__ __forceinline__ float4 conv_silu4(const float* __restrict__ part2,
    const float* __restrict__ cw, const float* __restrict__ cb, int R, int d0) {
  int bq = R / 9, pq = R - bq * 9;
  size_t rb = (size_t)R * (2 * NIN) + d0;
  size_t SL = (size_t)Mn * 2 * NIN;
  float cx[4] = {0.f, 0.f, 0.f, 0.f}, cm[4] = {0.f, 0.f, 0.f, 0.f}, cp[4] = {0.f, 0.f, 0.f, 0.f};
  #pragma unroll
  for (int sl = 0; sl < KS2; ++sl) {
    float4 a = *reinterpret_cast<const float4*>(part2 + sl * SL + rb);
    cx[0] += a.x; cx[1] += a.y; cx[2] += a.z; cx[3] += a.w;
    if (pq > 0) {
      float4 m = *reinterpret_cast<const float4*>(part2 + sl * SL + rb - 2 * NIN);
      cm[0] += m.x; cm[1] += m.y; cm[2] += m.z; cm[3] += m.w;
    }
    if (pq < Ln - 1) {
      float4 q = *reinterpret_cast<const float4*>(part2 + sl * SL + rb + 2 * NIN);
      cp[0] += q.x; cp[1] += q.y; cp[2] += q.z; cp[3] += q.w;
    }
  }
  float4 w0 = *reinterpret_cast<const float4*>(cw + 3 * d0);
  float4 w1 = *reinterpret_cast<const float4*>(cw + 3 * d0 + 4);
  float4 w2 = *reinterpret_cast<const float4*>(cw + 3 * d0 + 8);
  float wf[12] = {w0.x, w0.y, w0.z, w0.w, w1.x, w1.y, w1.z, w1.w, w2.x, w2.y, w2.z, w2.w};
  float4 cb4 = *reinterpret_cast<const float4*>(cb + d0);
  float cbf[4] = {cb4.x, cb4.y, cb4.z, cb4.w};
  float r[4];
  #pragma unroll
  for (int i = 0; i < 4; ++i) {
    float a = cbf[i] + cm[i] * wf[3 * i] + cx[i] * wf[3 * i + 1] + cp[i] * wf[3 * i + 2];
    r[i] = a / (1.0f + __expf(-a));
  }
  return make_float4(r[0], r[1], r[2], r[3]);
}

// ---------------- xproj split-K partials (fp32), conv+silu fused into A staging ----------
__global__ __launch_bounds__(256) void xproj_kernel(const float* __restrict__ part2,
    const float* __restrict__ cw, const float* __restrict__ cb,
    const float* __restrict__ w, float* __restrict__ part) {
  __shared__ float at[64][44];
  __shared__ float wt[32][80];
  int kc = blockIdx.x, mt = blockIdx.y;
  int t = threadIdx.x;
  int tx = t & 15, ty = t >> 4;
  float acc[4][5] = {};
  int sr = t >> 3, sc4 = (t & 7) * 4;
  for (int k0 = kc * 96; k0 < kc * 96 + 96; k0 += 32) {
    float4 v0 = conv_silu4(part2, cw, cb, mt * 64 + sr,      k0 + sc4);
    float4 v1 = conv_silu4(part2, cw, cb, mt * 64 + sr + 32, k0 + sc4);
    __syncthreads();
    *reinterpret_cast<float4*>(&at[sr][sc4])      = v0;
    *reinterpret_cast<float4*>(&at[sr + 32][sc4]) = v1;
    for (int i = t; i < 32 * 80; i += 256)
      wt[i / 80][i % 80] = w[(size_t)(k0 + i / 80) * 80 + i % 80];
    __syncthreads();
    #pragma unroll
    for (int kk = 0; kk < 32; ++kk) {
      float a0[4], b0[5];
      #pragma unroll
      for (int i = 0; i < 4; ++i) a0[i] = at[ty * 4 + i][kk];
      #pragma unroll
      for (int j = 0; j < 5; ++j) b0[j] = wt[kk][tx + 16 * j];
      #pragma unroll
      for (int i = 0; i < 4; ++i)
        #pragma unroll
        for (int j = 0; j < 5; ++j)
          acc[i][j] = fmaf(a0[i], b0[j], acc[i][j]);
    }
  }
  #pragma unroll
  for (int i = 0; i < 4; ++i)
    #pragma unroll
    for (int j = 0; j < 5; ++j)
      part[((size_t)kc * Mn + mt * 64 + ty * 4 + i) * 80 + tx + 16 * j] = acc[i][j];
}

// ---------------- fused: split-K reduce + pe_b bias + LayerNorm -> interleaved h2 --------
__global__ __launch_bounds__(256) void ln_kernel(const float* __restrict__ part1,
    const float* __restrict__ peb, const float* __restrict__ g, const float* __restrict__ be,
    unsigned short* __restrict__ h2) {
  int row = blockIdx.x;
  int t = threadIdx.x;
  float vq[3];
  #pragma unroll
  for (int q = 0; q < 3; ++q) {
    int c = t + q * 256;
    float v = peb[c];
    #pragma unroll
    for (int ks = 0; ks < 8; ++ks)
      v += part1[((size_t)ks * Mn + row) * HID + c];
    vq[q] = v;
  }
  float s  = vq[0] + vq[1] + vq[2];
  float s2 = vq[0] * vq[0] + vq[1] * vq[1] + vq[2] * vq[2];
  #pragma unroll
  for (int o = 32; o > 0; o >>= 1) {
    s  += __shfl_down(s,  o, 64);
    s2 += __shfl_down(s2, o, 64);
  }
  __shared__ float red[8];
  int wid = t >> 6, lane = t & 63;
  if (lane == 0) { red[wid] = s; red[4 + wid] = s2; }
  __syncthreads();
  float S  = red[0] + red[1] + red[2] + red[3];
  float S2 = red[4] + red[5] + red[6] + red[7];
  float mu  = S * (1.0f / HID);
  float var = S2 * (1.0f / HID) - mu * mu;
  float inv = rsqrtf(var + 1e-5f);
  #pragma unroll
  for (int q = 0; q < 3; ++q) {
    int c = t + q * 256;
    float hv = (vq[q] - mu) * inv * g[c] + be[c];
    unsigned short hi, lo;
    split_bf(hv, hi, lo);
    size_t base = (size_t)row * (2 * HID) + col2(c);
    h2[base] = hi; h2[base + 32] = lo;
  }
}

// -- fused scan: xproj reduce + dt-proj + softplus + conv-recompute + scan + D + z-gate --
__global__ __launch_bounds__(256) void scan_kernel(const float* __restrict__ partx,
    const float* __restrict__ A_log, const float* __restrict__ Dp,
    const float* __restrict__ part2, const float* __restrict__ dtw,
    const float* __restrict__ dtb, const float* __restrict__ cw,
    const float* __restrict__ cb, unsigned short* __restrict__ ya2) {
  __shared__ float wdt[DTR * 256];                    // 48 KB
  __shared__ float dbc9[Ln][DTR];
  __shared__ float Bsh[Ln][NST], Csh[Ln][NST];
  int b      = blockIdx.x / (NIN / 256);
  int dchunk = blockIdx.x % (NIN / 256);
  int t = threadIdx.x;
  float4* w4 = reinterpret_cast<float4*>(wdt);
  #pragma unroll
  for (int it = 0; it < 12; ++it) {
    int i4 = it * 256 + t;
    int k = i4 >> 6, c4 = i4 & 63;
    w4[i4] = *reinterpret_cast<const float4*>(dtw + (size_t)k * NIN + dchunk * 256 + c4 * 4);
  }
  for (int i = t; i < Ln * 80; i += 256) {
    int p = i / 80, k = i - p * 80;
    size_t off = (size_t)(b * Ln + p) * 80 + k;
    float s = 0.f;
    #pragma unroll
    for (int ks = 0; ks < XKS; ++ks) s += partx[(size_t)ks * (Mn * 80) + off];
    if (k < DTR)            dbc9[p][k] = s;
    else if (k < DTR + NST) Bsh[p][k - DTR] = s;
    else                    Csh[p][k - DTR - NST] = s;
  }
  __syncthreads();
  int d = dchunk * 256 + t;
  float Ar[NST];
  #pragma unroll
  for (int n = 0; n < NST; ++n) Ar[n] = -__expf(A_log[(size_t)d * NST + n]);
  float s[NST];
  #pragma unroll
  for (int n = 0; n < NST; ++n) s[n] = 0.0f;
  float Dv = Dp[d];
  float bt = dtb[d];
  float w0 = cw[3 * d], w1 = cw[3 * d + 1], w2 = cw[3 * d + 2];
  float cbv = cb[d];
  int cc = col2(d);
  size_t SL = (size_t)Mn * 2 * NIN;
  const float* px = part2 + d;                        // x-half
  const float* pz = part2 + NIN + d;                  // z-half
  size_t row0 = (size_t)(b * Ln) * (2 * NIN);
  float xm = 0.f;
  float x0 = 0.f;
  #pragma unroll
  for (int sl = 0; sl < KS2; ++sl) x0 += px[sl * SL + row0];
  for (int p = 0; p < Ln; ++p) {
    size_t roff = row0 + (size_t)p * (2 * NIN);
    float xp = 0.f;
    if (p < Ln - 1) {
      #pragma unroll
      for (int sl = 0; sl < KS2; ++sl) xp += px[sl * SL + roff + 2 * NIN];
    }
    float a0 = cbv + xm * w0 + x0 * w1 + xp * w2;
    float u = a0 / (1.0f + __expf(-a0));              // silu(conv)
    float a = bt;
    #pragma unroll
    for (int k = 0; k < DTR; ++k) a = fmaf(dbc9[p][k], wdt[k * 256 + t], a);
    float dl = fmaxf(a, 0.0f) + log1pf(__expf(-fabsf(a)));
    float du = dl * u;
    float y = 0.0f;
    #pragma unroll
    for (int n = 0; n < NST; ++n) {
      float dA = __expf(dl * Ar[n]);
      s[n] = dA * s[n] + du * Bsh[p][n];
      y += s[n] * Csh[p][n];
    }
    float zv = 0.f;
    #pragma unroll
    for (int sl = 0; sl < KS2; ++sl) zv += pz[sl * SL + roff];
    float sz = zv / (1.0f + __expf(-zv));
    float yv = (y + u * Dv) * sz;
    unsigned short hi, lo;
    split_bf(yv, hi, lo);
    ya2[roff + cc] = hi; ya2[roff + cc + 32] = lo;
    xm = x0; x0 = xp;
  }
}

// -------- fused: split-K reduce + transpose + bilinear resize, coalesced writes --------
__global__ __launch_bounds__(256) void resize_kernel(const float* __restrict__ part3,
                                                     float* __restrict__ out) {
  __shared__ float v[32][10];
  int blk = blockIdx.x;                               // Bn * (Cn/32) = 8192
  int b = blk >> 6, cg = blk & 63;
  int t = threadIdx.x;
  size_t MN3 = (size_t)Mn * Cn;
  for (int i = t; i < 288; i += 256) {
    int p = i >> 5, c = i & 31;
    size_t base = (size_t)(b * Ln + p) * Cn + cg * 32 + c;
    float s = 0.f;
    #pragma unroll
    for (int sl = 0; sl < KS3; ++sl) s += part3[base + sl * MN3];
    v[c][p] = s;
  }
  __syncthreads();
  int ch = t >> 3, sub = t & 7;
  float* dst = out + ((size_t)b * Cn + cg * 32 + ch) * 288;
  #pragma unroll
  for (int q = 0; q < 9; ++q) {
    int f = sub + q * 8;
    int y = f / 3, xq = f - y * 3;
    float fy  = (y + 0.5f) * 0.125f - 0.5f;
    float fyf = floorf(fy);
    float wy  = fy - fyf;
    int yy = (int)fyf;
    int y0 = min(2, max(0, yy)), y1 = min(2, max(0, yy + 1));
    float rr[3];
    #pragma unroll
    for (int j = 0; j < 3; ++j)
      rr[j] = v[ch][y0 * 3 + j] * (1.0f - wy) + v[ch][y1 * 3 + j] * wy;
    float ov[4];
    #pragma unroll
    for (int xi = 0; xi < 4; ++xi) {
      int xo = xq * 4 + xi;
      float fx  = (xo + 0.5f) * 0.25f - 0.5f;
      float fxf = floorf(fx);
      float wx  = fx - fxf;
      int xx = (int)fxf;
      int x0 = min(2, max(0, xx)), x1 = min(2, max(0, xx + 1));
      ov[xi] = rr[x0] * (1.0f - wx) + rr[x1] * wx;
    }
    *reinterpret_cast<float4*>(dst + f * 4) = make_float4(ov[0], ov[1], ov[2], ov[3]);
  }
}

extern "C" void kernel_launch(void* const* d_in, const int* in_sizes, int n_in,
                              void* d_out, int out_size, void* d_ws, size_t ws_size,
                              hipStream_t stream) {
  const float* x        = (const float*)d_in[0];
  const float* pe_w     = (const float*)d_in[1];
  const float* pe_b     = (const float*)d_in[2];
  const float* ln_g     = (const float*)d_in[3];
  const float* ln_b     = (const float*)d_in[4];
  const float* in_w     = (const float*)d_in[5];
  const float* conv_w   = (const float*)d_in[6];
  const float* conv_b   = (const float*)d_in[7];
  const float* A_log    = (const float*)d_in[8];
  const float* xproj_w  = (const float*)d_in[9];
  const float* dtproj_w = (const float*)d_in[10];
  const float* dtproj_b = (const float*)d_in[11];
  const float* D_param  = (const float*)d_in[12];
  const float* out_w    = (const float*)d_in[13];
  float* out = (float*)d_out;
  char* ws = (char*)d_ws;

  size_t o = 0;
  auto alloc = [&](size_t bytes) { size_t r = o; o += (bytes + 255) & ~(size_t)255; return r; };
  unsigned short* tok2  = (unsigned short*)(ws + alloc((size_t)Mn * 2 * Cn * 2));
  unsigned short* peT2  = (unsigned short*)(ws + alloc((size_t)HID * 2 * Cn * 2));
  unsigned short* inT2  = (unsigned short*)(ws + alloc((size_t)2 * NIN * 2 * HID * 2));
  unsigned short* outT2 = (unsigned short*)(ws + alloc((size_t)Cn * 2 * NIN * 2));
  unsigned short* h2    = (unsigned short*)(ws + alloc((size_t)Mn * 2 * HID * 2));
  unsigned short* ya2   = (unsigned short*)(ws + alloc((size_t)Mn * 2 * NIN * 2));
  float* part1 = (float*)(ws + alloc((size_t)8 * Mn * HID * 4));
  float* part2 = (float*)(ws + alloc((size_t)KS2 * Mn * 2 * NIN * 4));
  float* part3 = (float*)(ws + alloc((size_t)KS3 * Mn * Cn * 4));
  float* partx = (float*)(ws + alloc((size_t)XKS * Mn * 80 * 4));

  // prep: weight transposes (6912 blocks) + pooling (8192 blocks)
  prep_kernel<<<15104, 256, 0, stream>>>(pe_w, in_w, out_w, x, peT2, inT2, outT2, tok2);

  // tok @ pe_w : M=1152 N=768 K=2048, split-K=8 -> grid 432 (6*9*8)
  mgemm_kernel<<<dim3(HID / 128, Mn / 128, 8), 256, 0, stream>>>(
      tok2, peT2, part1, Mn, HID, Cn, Cn / 8);
  ln_kernel<<<Mn, 256, 0, stream>>>(part1, pe_b, ln_g, ln_b, h2);
  // h @ in_w : M=1152 N=3072 K=768, split-K=3 -> grid 648 (24*9*3)
  mgemm_kernel<<<dim3(2 * NIN / 128, Mn / 128, KS2), 256, 0, stream>>>(
      h2, inT2, part2, Mn, 2 * NIN, HID, HID / KS2);
  xproj_kernel<<<dim3(XKS, Mn / 64), 256, 0, stream>>>(part2, conv_w, conv_b, xproj_w, partx);
  scan_kernel<<<Bn * (NIN / 256), 256, 0, stream>>>(
      partx, A_log, D_param, part2, dtproj_w, dtproj_b, conv_w, conv_b, ya2);
  // ya @ out_w : M=1152 N=2048 K=1536, split-K=4 -> grid 576 (16*9*4)
  mgemm_kernel<<<dim3(Cn / 128, Mn / 128, KS3), 256, 0, stream>>>(
      ya2, outT2, part3, Mn, Cn, NIN, NIN / KS3);
  resize_kernel<<<Bn * (Cn / 32), 256, 0, stream>>>(part3, out);
}